// Round 2
// baseline (1312.867 us; speedup 1.0000x reference)
//
#include <hip/hip_runtime.h>

#define NPTS    131072     // 32 * 64 * 64 points
#define KC      1024       // codes
#define DD      64         // embedding dim
#define HWSZ    4096       // h*w
#define MARGINF 6e-5f      // packed-domain gap below which we refine on the f32 grid

typedef __attribute__((ext_vector_type(8))) short short8;  // 8 bf16 = 4 VGPRs
typedef __attribute__((ext_vector_type(4))) float f32x4;   // MFMA C/D frag

__device__ __forceinline__ ushort bf16_rne(float x) {
    unsigned u = __float_as_uint(x);
    unsigned r = u + 0x7fffu + ((u >> 16) & 1u);
    return (ushort)(r >> 16);
}

// numpy pairwise sum, n=64 contiguous path: 8 accumulators, exact order.
__device__ __forceinline__ float np_pairwise64(const float* a) {
#pragma clang fp contract(off)
    float r0 = a[0], r1 = a[1], r2 = a[2], r3 = a[3];
    float r4 = a[4], r5 = a[5], r6 = a[6], r7 = a[7];
    for (int i = 8; i < 64; i += 8) {
        r0 += a[i + 0]; r1 += a[i + 1]; r2 += a[i + 2]; r3 += a[i + 3];
        r4 += a[i + 4]; r5 += a[i + 5]; r6 += a[i + 6]; r7 += a[i + 7];
    }
    return ((r0 + r1) + (r2 + r3)) + ((r4 + r5) + (r6 + r7));
}

// ---- E prep: numpy-order ||e||^2, biased copy, MFMA-fragment-ordered bf16,
//      plus a d-major transpose embT[d][k] for the coalesced fix kernel. -----
__global__ void vq_prep_e(const float* __restrict__ emb, float* __restrict__ se32,
                          float* __restrict__ sebB, ushort* __restrict__ Ebuf,
                          float* __restrict__ embT) {
    int k = blockIdx.x * blockDim.x + threadIdx.x;
    if (k >= KC) return;
    const float* e = emb + k * DD;
    float sq[DD];
    {
#pragma clang fp contract(off)
        for (int d = 0; d < DD; ++d) sq[d] = e[d] * e[d];
    }
    float s = np_pairwise64(sq);
    se32[k] = s;
    sebB[k] = s + 0.5f;                 // bias keeps scan scores strictly positive
    const int tile = k >> 4, colk = k & 15;
    for (int d = 0; d < DD; ++d) {
        int kh = d >> 5, quad = (d & 31) >> 3, jj = d & 7;
        float ev = e[d];
        embT[d * KC + k] = ev;          // coalesced across threads (consecutive k)
        ushort hb = bf16_rne(ev);
        float  hf = __uint_as_float(((unsigned)hb) << 16);
        ushort lb = bf16_rne(ev - hf);
        int pos = (quad * 16 + colk) * 8 + jj;
        Ebuf[((tile * 2 + kh) * 2 + 0) * 512 + pos] = hb;
        Ebuf[((tile * 2 + kh) * 2 + 1) * 512 + pos] = lb;
    }
}

// ---- fused: stage x -> A frags -> MFMA scan (packed-uint argmin) -> outputs
__global__ void __launch_bounds__(256)
vq_main(const float* __restrict__ in, const float* __restrict__ emb,
        const ushort* __restrict__ Ebuf, const float* __restrict__ sebB,
        float* __restrict__ outq, float* __restrict__ outl, float* __restrict__ outi,
        int* __restrict__ cnt, int* __restrict__ queue) {
    __shared__ float xs[64][129];   // [c][j], pad -> conflict-light both ways (33 KB)
    __shared__ int   sidx[128];
    const int tid = threadIdx.x;
    const int n0  = blockIdx.x * 128;     // 128 consecutive points, single batch image
    const int b   = n0 >> 12;
    const int hw0 = n0 & 4095;
    const float* inb = in + (size_t)b * DD * HWSZ;

    // stage exact x for the block's 128 points (coalesced over hw)
#pragma unroll
    for (int it = 0; it < 32; ++it) {
        int f = tid + it * 256;
        int c = f >> 7, j = f & 127;
        xs[c][j] = inb[c * HWSZ + hw0 + j];
    }
    __syncthreads();

    const int lane = tid & 63, wave = tid >> 6;
    const int quad = lane >> 4, col = lane & 15;

    // A fragments (bf16 hi/lo) straight from LDS — no global X roundtrip
    short8 A[2][2][2];   // [psub][khalf][hi/lo]
#pragma unroll
    for (int p = 0; p < 2; ++p) {
        int pt = wave * 32 + p * 16 + col;
#pragma unroll
        for (int kh = 0; kh < 2; ++kh) {
            short8 ah, al;
#pragma unroll
            for (int j = 0; j < 8; ++j) {
                float xv = xs[kh * 32 + quad * 8 + j][pt];
                ushort hb = bf16_rne(xv);
                float  hf = __uint_as_float(((unsigned)hb) << 16);
                ah[j] = (short)hb;
                al[j] = (short)bf16_rne(xv - hf);
            }
            A[p][kh][0] = ah; A[p][kh][1] = al;
        }
    }

    unsigned b1[8], b2[8];          // packed: (score+0.5 bits & ~63) | tile
#pragma unroll
    for (int s = 0; s < 8; ++s) { b1[s] = 0xFFFFFFFFu; b2[s] = 0xFFFFFFFFu; }

    for (int g = 0; g < 16; ++g) {            // 64 codes per iteration
        short8 B[4][2][2];
        float  sB[4];
#pragma unroll
        for (int s = 0; s < 4; ++s) {
            int tile = g * 4 + s;
            sB[s] = sebB[tile * 16 + col];
#pragma unroll
            for (int kh = 0; kh < 2; ++kh)
#pragma unroll
                for (int hl = 0; hl < 2; ++hl)
                    B[s][kh][hl] = *(const short8*)(Ebuf + ((tile * 2 + kh) * 2 + hl) * 512 + lane * 8);
        }
        f32x4 acc[2][4];
#pragma unroll
        for (int p = 0; p < 2; ++p)
#pragma unroll
            for (int s = 0; s < 4; ++s) acc[p][s] = (f32x4){0.f, 0.f, 0.f, 0.f};
#pragma unroll
        for (int p = 0; p < 2; ++p)
#pragma unroll
            for (int s = 0; s < 4; ++s) {
                acc[p][s] = __builtin_amdgcn_mfma_f32_16x16x32_bf16(A[p][0][0], B[s][0][0], acc[p][s], 0, 0, 0);
                acc[p][s] = __builtin_amdgcn_mfma_f32_16x16x32_bf16(A[p][1][0], B[s][1][0], acc[p][s], 0, 0, 0);
                acc[p][s] = __builtin_amdgcn_mfma_f32_16x16x32_bf16(A[p][0][0], B[s][0][1], acc[p][s], 0, 0, 0);
                acc[p][s] = __builtin_amdgcn_mfma_f32_16x16x32_bf16(A[p][1][0], B[s][1][1], acc[p][s], 0, 0, 0);
                acc[p][s] = __builtin_amdgcn_mfma_f32_16x16x32_bf16(A[p][0][1], B[s][0][0], acc[p][s], 0, 0, 0);
                acc[p][s] = __builtin_amdgcn_mfma_f32_16x16x32_bf16(A[p][1][1], B[s][1][0], acc[p][s], 0, 0, 0);
            }
        // packed-uint fold: 4 codes per slot via sorted-2-of-4 insertion
#pragma unroll
        for (int p = 0; p < 2; ++p)
#pragma unroll
            for (int r = 0; r < 4; ++r) {
                unsigned q[4];
#pragma unroll
                for (int s = 0; s < 4; ++s) {
                    float t = fmaf(-2.f, acc[p][s][r], sB[s]);       // 0.5 + se - 2x.e > 0
                    q[s] = (__float_as_uint(t) & 0xFFFFFFC0u) | (unsigned)(g * 4 + s);
                }
                unsigned a  = min(q[0], q[1]), bb = max(q[0], q[1]);
                unsigned c2 = min(q[2], q[3]), d2 = max(q[2], q[3]);
                unsigned lo = min(a, c2), hi = max(a, c2);
                unsigned sec = min(min(bb, d2), hi);                  // 2nd smallest of 4
                int sl = p * 4 + r;
                b2[sl] = min(min(b2[sl], sec), max(b1[sl], lo));
                b1[sl] = min(b1[sl], lo);
            }
    }

    // decode + 16-col butterfly merge (first-index tie-break)
    unsigned v1[8], v2[8]; int ci[8];
#pragma unroll
    for (int s = 0; s < 8; ++s) {
        ci[s] = (int)(b1[s] & 63u) * 16 + col;
        v1[s] = b1[s] & 0xFFFFFFC0u;
        v2[s] = b2[s] & 0xFFFFFFC0u;
    }
#pragma unroll
    for (int off = 1; off < 16; off <<= 1) {
#pragma unroll
        for (int s = 0; s < 8; ++s) {
            unsigned o1 = (unsigned)__shfl_xor((int)v1[s], off);
            unsigned o2 = (unsigned)__shfl_xor((int)v2[s], off);
            int      oi = __shfl_xor(ci[s], off);
            unsigned nb2 = min(min(v2[s], o2), max(v1[s], o1));
            bool take = (o1 < v1[s]) || (o1 == v1[s] && oi < ci[s]);
            v1[s] = take ? o1 : v1[s];
            ci[s] = take ? oi : ci[s];
            v2[s] = nb2;
        }
    }
#pragma unroll
    for (int s = 0; s < 8; ++s) {
        if (col == s) {
            int jloc = wave * 32 + (s >> 2) * 16 + quad * 4 + (s & 3);
            sidx[jloc] = ci[s];
            float f1 = __uint_as_float(v1[s]), f2 = __uint_as_float(v2[s]);
            if (f2 - f1 < MARGINF) { int pos = atomicAdd(cnt, 1); queue[pos] = n0 + jloc; }
        }
    }
    __syncthreads();

    // fused output epilogue: lane -> channel, loop over this wave's 32 points
    for (int t = 0; t < 32; ++t) {
        int jloc = wave * 32 + t;
        int kidx = sidx[jloc];
        float qv = emb[kidx * DD + lane];              // coalesced 256B row, L2-hot
        float x  = xs[lane][jloc];
        float dv = qv - x;
        float l  = dv * dv;
        outl[(size_t)(n0 + jloc) * DD + lane] = fmaf(0.25f, l, l);   // coalesced
        outq[((size_t)(b * DD) + lane) * HWSZ + hw0 + jloc] = x + (qv - x);  // L2-merged scatter
    }
    if (lane < 32) outi[n0 + wave * 32 + lane] = (float)sidx[wave * 32 + lane];
}

// ---- fix: emulate numpy f32 dists grid for queued points, rewrite if changed
// Restructured: lane l owns x[l] (1 VGPR, readlane-broadcast per d);
// k = lane*16 + j so each lane streams 64 contiguous bytes of embT row d
// (4x dwordx4, wave covers the full 4KB row); 16 independent f64 chains
// hide FMA latency. Per-k accumulation order over d is IDENTICAL to the
// previous serial version -> bit-identical f32-grid values and argmin.
__global__ void __launch_bounds__(256, 4)
vq_fix(const float* __restrict__ in, const float* __restrict__ emb,
       const float* __restrict__ embT, const float* __restrict__ se32,
       const int* __restrict__ queue, const int* __restrict__ cnt,
       float* __restrict__ outq, float* __restrict__ outl, float* __restrict__ outi) {
    const int lane = threadIdx.x & 63;
    const int gw   = blockIdx.x * 4 + (threadIdx.x >> 6);
    const int nwav = gridDim.x * 4;
    const int total = *cnt;
    for (int qi = gw; qi < total; qi += nwav) {
        const int n  = queue[qi];
        const int b  = n >> 12, hw = n & 4095;
        const float* inb = in + (size_t)b * DD * HWSZ + hw;
        const float xr = inb[lane * HWSZ];        // lane d holds x[d]

        double acc[16];
#pragma unroll
        for (int j = 0; j < 16; ++j) acc[j] = 0.0;
        float rr[8];                              // numpy pairwise accumulators

#pragma unroll
        for (int d = 0; d < 64; ++d) {            // fully unrolled: static indices
            float xv = __int_as_float(__builtin_amdgcn_readlane(__float_as_int(xr), d));
            {
#pragma clang fp contract(off)
                float t = xv * xv;                // separate mul+add, numpy order
                if (d < 8) rr[d] = t;
                else       rr[d & 7] += t;
            }
            const float* rp = embT + (size_t)d * KC + (lane << 4);
            f32x4 e0 = *(const f32x4*)(rp + 0);
            f32x4 e1 = *(const f32x4*)(rp + 4);
            f32x4 e2 = *(const f32x4*)(rp + 8);
            f32x4 e3 = *(const f32x4*)(rp + 12);
            double xd = (double)xv;
#pragma unroll
            for (int j = 0; j < 4; ++j) {
                acc[j +  0] = fma(xd, (double)e0[j], acc[j +  0]);
                acc[j +  4] = fma(xd, (double)e1[j], acc[j +  4]);
                acc[j +  8] = fma(xd, (double)e2[j], acc[j +  8]);
                acc[j + 12] = fma(xd, (double)e3[j], acc[j + 12]);
            }
        }
        float sx;
        {
#pragma clang fp contract(off)
            sx = ((rr[0] + rr[1]) + (rr[2] + rr[3])) + ((rr[4] + rr[5]) + (rr[6] + rr[7]));
        }

        float bD = 3.4e38f; int bi = 0x7fffffff;
#pragma unroll
        for (int j = 0; j < 16; ++j) {            // ascending k within lane
            int k = (lane << 4) + j;
            float m2 = (float)(2.0 * acc[j]);     // ~= f32 sgemm result (single rounding)
            float s1, Dv;
            {
#pragma clang fp contract(off)
                s1 = sx + se32[k];
                Dv = s1 - m2;                     // the reference's f32 grid value
            }
            if (Dv < bD) { bD = Dv; bi = k; }
        }
#pragma unroll
        for (int off = 32; off > 0; off >>= 1) {
            float oD = __shfl_down(bD, off);
            int   oi = __shfl_down(bi, off);
            if (oD < bD || (oD == bD && oi < bi)) { bD = oD; bi = oi; }
        }
        bi = __shfl(bi, 0);                       // broadcast winner to all lanes
        int old = (int)outi[n];
        if (bi != old) {
            float xv = xr;                        // lane's own x[lane]
            float qv = emb[bi * DD + lane];
            float dv = qv - xv;
            float l  = dv * dv;
            outl[(size_t)n * DD + lane] = fmaf(0.25f, l, l);
            outq[((size_t)b * DD + lane) * HWSZ + hw] = xv + (qv - xv);
            if (lane == 0) outi[n] = (float)bi;
        }
    }
}

extern "C" void kernel_launch(void* const* d_in, const int* in_sizes, int n_in,
                              void* d_out, int out_size, void* d_ws, size_t ws_size,
                              hipStream_t stream) {
    const float* in  = (const float*)d_in[0];   // (32,64,64,64) bchw f32
    const float* emb = (const float*)d_in[1];   // (1024,64) f32

    float* outq = (float*)d_out;                        // 8388608
    float* outl = outq + (size_t)NPTS * DD;             // 8388608
    float* outi = outl + (size_t)NPTS * DD;             // 131072 (idx as f32)

    char*   ws    = (char*)d_ws;                        // ~1.05 MB used
    float*  se32  = (float*)ws;                         // 4 KB
    float*  sebB  = (float*)(ws + 4096);                // 4 KB
    ushort* Ebuf  = (ushort*)(ws + 8192);               // 256 KB (frag-ordered hi/lo)
    float*  embT  = (float*)(ws + 8192 + 262144);       // 256 KB (d-major transpose)
    int*    cnt   = (int*)(ws + 8192 + 262144 + 262144);
    int*    queue = (int*)(ws + 8192 + 262144 + 262144 + 256);  // NPTS*4 worst case

    hipMemsetAsync(cnt, 0, sizeof(int), stream);
    vq_prep_e<<<4, 256, 0, stream>>>(emb, se32, sebB, Ebuf, embT);
    vq_main<<<NPTS / 128, 256, 0, stream>>>(in, emb, Ebuf, sebB, outq, outl, outi, cnt, queue);
    vq_fix<<<512, 256, 0, stream>>>(in, emb, embT, se32, queue, cnt, outq, outl, outi);
}

// Round 3
// 230.611 us; speedup vs baseline: 5.6930x; 5.6930x over previous
//
#include <hip/hip_runtime.h>

#define NPTS    131072     // 32 * 64 * 64 points
#define KC      1024       // codes
#define DD      64         // embedding dim
#define HWSZ    4096       // h*w
#define MARGINF 6e-5f      // packed-domain gap below which we refine on the f32 grid

typedef __attribute__((ext_vector_type(8))) short short8;  // 8 bf16 = 4 VGPRs
typedef __attribute__((ext_vector_type(4))) float f32x4;   // MFMA C/D frag

__device__ __forceinline__ ushort bf16_rne(float x) {
    unsigned u = __float_as_uint(x);
    unsigned r = u + 0x7fffu + ((u >> 16) & 1u);
    return (ushort)(r >> 16);
}

// numpy pairwise sum, n=64 contiguous path: 8 accumulators, exact order.
__device__ __forceinline__ float np_pairwise64(const float* a) {
#pragma clang fp contract(off)
    float r0 = a[0], r1 = a[1], r2 = a[2], r3 = a[3];
    float r4 = a[4], r5 = a[5], r6 = a[6], r7 = a[7];
    for (int i = 8; i < 64; i += 8) {
        r0 += a[i + 0]; r1 += a[i + 1]; r2 += a[i + 2]; r3 += a[i + 3];
        r4 += a[i + 4]; r5 += a[i + 5]; r6 += a[i + 6]; r7 += a[i + 7];
    }
    return ((r0 + r1) + (r2 + r3)) + ((r4 + r5) + (r6 + r7));
}

// ---- E prep: numpy-order ||e||^2, biased copy, MFMA-fragment-ordered bf16,
//      plus a d-major transpose embT[d][k] for the coalesced fix kernel. -----
__global__ void vq_prep_e(const float* __restrict__ emb, float* __restrict__ se32,
                          float* __restrict__ sebB, ushort* __restrict__ Ebuf,
                          float* __restrict__ embT) {
    int k = blockIdx.x * blockDim.x + threadIdx.x;
    if (k >= KC) return;
    const float* e = emb + k * DD;
    float sq[DD];
    {
#pragma clang fp contract(off)
        for (int d = 0; d < DD; ++d) sq[d] = e[d] * e[d];
    }
    float s = np_pairwise64(sq);
    se32[k] = s;
    sebB[k] = s + 0.5f;                 // bias keeps scan scores strictly positive
    const int tile = k >> 4, colk = k & 15;
    for (int d = 0; d < DD; ++d) {
        int kh = d >> 5, quad = (d & 31) >> 3, jj = d & 7;
        float ev = e[d];
        embT[d * KC + k] = ev;          // coalesced across threads (consecutive k)
        ushort hb = bf16_rne(ev);
        float  hf = __uint_as_float(((unsigned)hb) << 16);
        ushort lb = bf16_rne(ev - hf);
        int pos = (quad * 16 + colk) * 8 + jj;
        Ebuf[((tile * 2 + kh) * 2 + 0) * 512 + pos] = hb;
        Ebuf[((tile * 2 + kh) * 2 + 1) * 512 + pos] = lb;
    }
}

// ---- fused: stage x -> A frags -> MFMA scan (packed-uint argmin) -> outputs
__global__ void __launch_bounds__(256)
vq_main(const float* __restrict__ in, const float* __restrict__ emb,
        const ushort* __restrict__ Ebuf, const float* __restrict__ sebB,
        float* __restrict__ outq, float* __restrict__ outl, float* __restrict__ outi,
        int* __restrict__ cnt, int* __restrict__ queue) {
    __shared__ float xs[64][129];   // [c][j], pad -> conflict-light both ways (33 KB)
    __shared__ int   sidx[128];
    const int tid = threadIdx.x;
    const int n0  = blockIdx.x * 128;     // 128 consecutive points, single batch image
    const int b   = n0 >> 12;
    const int hw0 = n0 & 4095;
    const float* inb = in + (size_t)b * DD * HWSZ;

    // stage exact x for the block's 128 points (coalesced over hw)
#pragma unroll
    for (int it = 0; it < 32; ++it) {
        int f = tid + it * 256;
        int c = f >> 7, j = f & 127;
        xs[c][j] = inb[c * HWSZ + hw0 + j];
    }
    __syncthreads();

    const int lane = tid & 63, wave = tid >> 6;
    const int quad = lane >> 4, col = lane & 15;

    // A fragments (bf16 hi/lo) straight from LDS — no global X roundtrip
    short8 A[2][2][2];   // [psub][khalf][hi/lo]
#pragma unroll
    for (int p = 0; p < 2; ++p) {
        int pt = wave * 32 + p * 16 + col;
#pragma unroll
        for (int kh = 0; kh < 2; ++kh) {
            short8 ah, al;
#pragma unroll
            for (int j = 0; j < 8; ++j) {
                float xv = xs[kh * 32 + quad * 8 + j][pt];
                ushort hb = bf16_rne(xv);
                float  hf = __uint_as_float(((unsigned)hb) << 16);
                ah[j] = (short)hb;
                al[j] = (short)bf16_rne(xv - hf);
            }
            A[p][kh][0] = ah; A[p][kh][1] = al;
        }
    }

    unsigned b1[8], b2[8];          // packed: (score+0.5 bits & ~63) | tile
#pragma unroll
    for (int s = 0; s < 8; ++s) { b1[s] = 0xFFFFFFFFu; b2[s] = 0xFFFFFFFFu; }

    for (int g = 0; g < 16; ++g) {            // 64 codes per iteration
        short8 B[4][2][2];
        float  sB[4];
#pragma unroll
        for (int s = 0; s < 4; ++s) {
            int tile = g * 4 + s;
            sB[s] = sebB[tile * 16 + col];
#pragma unroll
            for (int kh = 0; kh < 2; ++kh)
#pragma unroll
                for (int hl = 0; hl < 2; ++hl)
                    B[s][kh][hl] = *(const short8*)(Ebuf + ((tile * 2 + kh) * 2 + hl) * 512 + lane * 8);
        }
        f32x4 acc[2][4];
#pragma unroll
        for (int p = 0; p < 2; ++p)
#pragma unroll
            for (int s = 0; s < 4; ++s) acc[p][s] = (f32x4){0.f, 0.f, 0.f, 0.f};
#pragma unroll
        for (int p = 0; p < 2; ++p)
#pragma unroll
            for (int s = 0; s < 4; ++s) {
                acc[p][s] = __builtin_amdgcn_mfma_f32_16x16x32_bf16(A[p][0][0], B[s][0][0], acc[p][s], 0, 0, 0);
                acc[p][s] = __builtin_amdgcn_mfma_f32_16x16x32_bf16(A[p][1][0], B[s][1][0], acc[p][s], 0, 0, 0);
                acc[p][s] = __builtin_amdgcn_mfma_f32_16x16x32_bf16(A[p][0][0], B[s][0][1], acc[p][s], 0, 0, 0);
                acc[p][s] = __builtin_amdgcn_mfma_f32_16x16x32_bf16(A[p][1][0], B[s][1][1], acc[p][s], 0, 0, 0);
                acc[p][s] = __builtin_amdgcn_mfma_f32_16x16x32_bf16(A[p][0][1], B[s][0][0], acc[p][s], 0, 0, 0);
                acc[p][s] = __builtin_amdgcn_mfma_f32_16x16x32_bf16(A[p][1][1], B[s][1][0], acc[p][s], 0, 0, 0);
            }
        // packed-uint fold: 4 codes per slot via sorted-2-of-4 insertion
#pragma unroll
        for (int p = 0; p < 2; ++p)
#pragma unroll
            for (int r = 0; r < 4; ++r) {
                unsigned q[4];
#pragma unroll
                for (int s = 0; s < 4; ++s) {
                    float t = fmaf(-2.f, acc[p][s][r], sB[s]);       // 0.5 + se - 2x.e > 0
                    q[s] = (__float_as_uint(t) & 0xFFFFFFC0u) | (unsigned)(g * 4 + s);
                }
                unsigned a  = min(q[0], q[1]), bb = max(q[0], q[1]);
                unsigned c2 = min(q[2], q[3]), d2 = max(q[2], q[3]);
                unsigned lo = min(a, c2), hi = max(a, c2);
                unsigned sec = min(min(bb, d2), hi);                  // 2nd smallest of 4
                int sl = p * 4 + r;
                b2[sl] = min(min(b2[sl], sec), max(b1[sl], lo));
                b1[sl] = min(b1[sl], lo);
            }
    }

    // decode + 16-col butterfly merge (first-index tie-break)
    unsigned v1[8], v2[8]; int ci[8];
#pragma unroll
    for (int s = 0; s < 8; ++s) {
        ci[s] = (int)(b1[s] & 63u) * 16 + col;
        v1[s] = b1[s] & 0xFFFFFFC0u;
        v2[s] = b2[s] & 0xFFFFFFC0u;
    }
#pragma unroll
    for (int off = 1; off < 16; off <<= 1) {
#pragma unroll
        for (int s = 0; s < 8; ++s) {
            unsigned o1 = (unsigned)__shfl_xor((int)v1[s], off);
            unsigned o2 = (unsigned)__shfl_xor((int)v2[s], off);
            int      oi = __shfl_xor(ci[s], off);
            unsigned nb2 = min(min(v2[s], o2), max(v1[s], o1));
            bool take = (o1 < v1[s]) || (o1 == v1[s] && oi < ci[s]);
            v1[s] = take ? o1 : v1[s];
            ci[s] = take ? oi : ci[s];
            v2[s] = nb2;
        }
    }
#pragma unroll
    for (int s = 0; s < 8; ++s) {
        if (col == s) {
            int jloc = wave * 32 + (s >> 2) * 16 + quad * 4 + (s & 3);
            sidx[jloc] = ci[s];
            float f1 = __uint_as_float(v1[s]), f2 = __uint_as_float(v2[s]);
            if (f2 - f1 < MARGINF) { int pos = atomicAdd(cnt, 1); queue[pos] = n0 + jloc; }
        }
    }
    __syncthreads();

    // fused output epilogue: lane -> channel, loop over this wave's 32 points
    for (int t = 0; t < 32; ++t) {
        int jloc = wave * 32 + t;
        int kidx = sidx[jloc];
        float qv = emb[kidx * DD + lane];              // coalesced 256B row, L2-hot
        float x  = xs[lane][jloc];
        float dv = qv - x;
        float l  = dv * dv;
        outl[(size_t)(n0 + jloc) * DD + lane] = fmaf(0.25f, l, l);   // coalesced
        outq[((size_t)(b * DD) + lane) * HWSZ + hw0 + jloc] = x + (qv - x);  // L2-merged scatter
    }
    if (lane < 32) outi[n0 + wave * 32 + lane] = (float)sidx[wave * 32 + lane];
}

// ---- fix: emulate numpy f32 dists grid for queued points, rewrite if changed
// Lane l owns x[l] (readlane-broadcast per d). Two passes of 8 f64 chains
// (j=0..7 then j=8..15) keep the live set ~50 VGPRs -> no scratch, unlike the
// 16-chain version (which spilled: 757MB fetch / 1GB write of scratch traffic).
// Per-k accumulation order over d is unchanged -> bit-identical f32 grid.
__global__ void __launch_bounds__(256)
vq_fix(const float* __restrict__ in, const float* __restrict__ emb,
       const float* __restrict__ embT, const float* __restrict__ se32,
       const int* __restrict__ queue, const int* __restrict__ cnt,
       float* __restrict__ outq, float* __restrict__ outl, float* __restrict__ outi) {
    const int lane = threadIdx.x & 63;
    const int gw   = blockIdx.x * 4 + (threadIdx.x >> 6);
    const int nwav = gridDim.x * 4;
    const int total = *cnt;
    for (int qi = gw; qi < total; qi += nwav) {
        const int n  = queue[qi];
        const int b  = n >> 12, hw = n & 4095;
        const float* inb = in + (size_t)b * DD * HWSZ + hw;
        const float xr = inb[lane * HWSZ];        // lane d holds x[d]

        float bD = 3.4e38f; int bi = 0x7fffffff;
        float sx;

        // ---- pass 0: this lane's codes j=0..7, plus ||x||^2 in numpy order
        {
            double acc[8];
            float rr[8];
#pragma unroll
            for (int j = 0; j < 8; ++j) { acc[j] = 0.0; rr[j] = 0.0f; }
            for (int dm = 0; dm < 8; ++dm) {        // outer may stay rolled
#pragma unroll
                for (int di = 0; di < 8; ++di) {    // static indices only
                    const int d = dm * 8 + di;
                    float xv = __int_as_float(
                        __builtin_amdgcn_readlane(__float_as_int(xr), d));
                    {
#pragma clang fp contract(off)
                        float t = xv * xv;          // squares are +0-signed:
                        rr[di] += t;                // 0+t == t bitwise, numpy order kept
                    }
                    const float* rp = embT + (size_t)d * KC + (lane << 4);
                    f32x4 e0 = *(const f32x4*)(rp + 0);
                    f32x4 e1 = *(const f32x4*)(rp + 4);
                    double xd = (double)xv;
#pragma unroll
                    for (int c4 = 0; c4 < 4; ++c4) {
                        acc[c4 + 0] = fma(xd, (double)e0[c4], acc[c4 + 0]);
                        acc[c4 + 4] = fma(xd, (double)e1[c4], acc[c4 + 4]);
                    }
                }
            }
            {
#pragma clang fp contract(off)
                sx = ((rr[0] + rr[1]) + (rr[2] + rr[3])) + ((rr[4] + rr[5]) + (rr[6] + rr[7]));
            }
#pragma unroll
            for (int j = 0; j < 8; ++j) {           // ascending k within lane
                int k = (lane << 4) + j;
                float m2 = (float)(2.0 * acc[j]);   // ~= f32 sgemm result (single rounding)
                float s1, Dv;
                {
#pragma clang fp contract(off)
                    s1 = sx + se32[k];
                    Dv = s1 - m2;                   // the reference's f32 grid value
                }
                if (Dv < bD) { bD = Dv; bi = k; }
            }
        }

        // ---- pass 1: this lane's codes j=8..15
        {
            double acc[8];
#pragma unroll
            for (int j = 0; j < 8; ++j) acc[j] = 0.0;
            for (int dm = 0; dm < 8; ++dm) {
#pragma unroll
                for (int di = 0; di < 8; ++di) {
                    const int d = dm * 8 + di;
                    float xv = __int_as_float(
                        __builtin_amdgcn_readlane(__float_as_int(xr), d));
                    const float* rp = embT + (size_t)d * KC + (lane << 4);
                    f32x4 e2 = *(const f32x4*)(rp + 8);
                    f32x4 e3 = *(const f32x4*)(rp + 12);
                    double xd = (double)xv;
#pragma unroll
                    for (int c4 = 0; c4 < 4; ++c4) {
                        acc[c4 + 0] = fma(xd, (double)e2[c4], acc[c4 + 0]);
                        acc[c4 + 4] = fma(xd, (double)e3[c4], acc[c4 + 4]);
                    }
                }
            }
#pragma unroll
            for (int j = 0; j < 8; ++j) {
                int k = (lane << 4) + 8 + j;
                float m2 = (float)(2.0 * acc[j]);
                float s1, Dv;
                {
#pragma clang fp contract(off)
                    s1 = sx + se32[k];
                    Dv = s1 - m2;
                }
                if (Dv < bD) { bD = Dv; bi = k; }
            }
        }

#pragma unroll
        for (int off = 32; off > 0; off >>= 1) {
            float oD = __shfl_down(bD, off);
            int   oi = __shfl_down(bi, off);
            if (oD < bD || (oD == bD && oi < bi)) { bD = oD; bi = oi; }
        }
        bi = __shfl(bi, 0);                       // broadcast winner to all lanes
        int old = (int)outi[n];
        if (bi != old) {
            float xv = xr;                        // lane's own x[lane]
            float qv = emb[bi * DD + lane];
            float dv = qv - xv;
            float l  = dv * dv;
            outl[(size_t)n * DD + lane] = fmaf(0.25f, l, l);
            outq[((size_t)b * DD + lane) * HWSZ + hw] = xv + (qv - xv);
            if (lane == 0) outi[n] = (float)bi;
        }
    }
}

extern "C" void kernel_launch(void* const* d_in, const int* in_sizes, int n_in,
                              void* d_out, int out_size, void* d_ws, size_t ws_size,
                              hipStream_t stream) {
    const float* in  = (const float*)d_in[0];   // (32,64,64,64) bchw f32
    const float* emb = (const float*)d_in[1];   // (1024,64) f32

    float* outq = (float*)d_out;                        // 8388608
    float* outl = outq + (size_t)NPTS * DD;             // 8388608
    float* outi = outl + (size_t)NPTS * DD;             // 131072 (idx as f32)

    char*   ws    = (char*)d_ws;                        // ~1.05 MB used
    float*  se32  = (float*)ws;                         // 4 KB
    float*  sebB  = (float*)(ws + 4096);                // 4 KB
    ushort* Ebuf  = (ushort*)(ws + 8192);               // 256 KB (frag-ordered hi/lo)
    float*  embT  = (float*)(ws + 8192 + 262144);       // 256 KB (d-major transpose)
    int*    cnt   = (int*)(ws + 8192 + 262144 + 262144);
    int*    queue = (int*)(ws + 8192 + 262144 + 262144 + 256);  // NPTS*4 worst case

    hipMemsetAsync(cnt, 0, sizeof(int), stream);
    vq_prep_e<<<4, 256, 0, stream>>>(emb, se32, sebB, Ebuf, embT);
    vq_main<<<NPTS / 128, 256, 0, stream>>>(in, emb, Ebuf, sebB, outq, outl, outi, cnt, queue);
    vq_fix<<<1024, 256, 0, stream>>>(in, emb, embT, se32, queue, cnt, outq, outl, outi);
}